// Round 6
// baseline (146.624 us; speedup 1.0000x reference)
//
#include <hip/hip_runtime.h>

#define BB 16
#define HH 2048
#define NN 1024
#define DD 2048
#define DG4 (DD / 4)   // 512 float4-groups per row

// One fused kernel, no inter-block communication.
// Block g: (a) recomputes softmax weighted_sum for ALL 16 batches (redundant
// across blocks, ~400 KB L2-hot per block), capturing ws fragments in regs;
// (b) computes output rows n = 4g..4g+3 for all 16 batches from prefetched
// V/F rows. V/F prefetch issued at t=0 hides the HBM stream under (a).
__global__ __launch_bounds__(512, 2) void ot_fused(const int* __restrict__ z,
                                                   const float* __restrict__ Fm,
                                                   const float* __restrict__ Vm,
                                                   const float* __restrict__ Wm,
                                                   float* __restrict__ out) {
    __shared__ float4 rows[8][DG4];      // 64 KB  (j = r*2 + m; m:0=V,1=F)
    __shared__ float  u[DD];             // 8 KB   W[d1,:]+W[d2,:] per batch
    __shared__ float  wsf[DD];           // 8 KB   scatter target per batch
    __shared__ int    hdrsh[2][BB];      // d1[b], d2[b]
    __shared__ float  redm[8], redt[8];
    __shared__ float  red[8][8][BB];     // 4 KB   (j, wave, b)

    const int tid  = threadIdx.x;
    const int lane = tid & 63;
    const int w    = tid >> 6;           // 0..7
    const int g    = blockIdx.x;
    const int b16  = tid & 15;           // this thread's batch in the dot
    const int s    = tid >> 4;           // 0..31 d-slot

    // ---- prefetch this block's 4 V/F rows into registers (issued first) ----
    float4 pf[8];
    {
        const int r = w >> 1, m = w & 1;
        const float4* __restrict__ src =
            (const float4*)((m ? Fm : Vm) + (size_t)(4 * g + r) * DD);
#pragma unroll
        for (int k = 0; k < 8; ++k) pf[k] = src[k * 64 + lane];
    }

    // ---- z tails -> d1,d2 for all batches ----
    if (tid < BB) {
        const int4 zt = ((const int4*)(z + (size_t)tid * HH))[DG4 - 1];
        hdrsh[0][tid] = zt.w;            // z[H-1]      in [0, NN)
        hdrsh[1][tid] = zt.z + NN;       // z[H-2]+NN   in [NN, DD)
    }
    __syncthreads();

    float4 wsr[16];                      // ws[d, b16] fragments (f32, exact)

    for (int b = 0; b < BB; ++b) {
        const int d1 = hdrsh[0][b], d2 = hdrsh[1][b];
        // stage u = W[d1,:] + W[d2,:]; zero wsf
        {
            float4 a = ((const float4*)(Wm + (size_t)d1 * DD))[tid];
            float4 c = ((const float4*)(Wm + (size_t)d2 * DD))[tid];
            float4 uu;
            uu.x = a.x + c.x; uu.y = a.y + c.y; uu.z = a.z + c.z; uu.w = a.w + c.w;
            ((float4*)u)[tid] = uu;
            ((float4*)wsf)[tid] = make_float4(0.f, 0.f, 0.f, 0.f);
        }
        __syncthreads();                                   // A

        // scores for h = 4*tid .. 4*tid+3
        const int4 zv = ((const int4*)(z + (size_t)b * HH))[tid];
        int zp0 = __shfl_up(zv.w, 1);
        if (lane == 0 && tid > 0) zp0 = z[(size_t)b * HH + 4 * tid - 1];

        const float s0 = u[zv.x] + ((tid > 0) ? u[zp0 + NN] : 0.f);
        const float s1 = u[zv.y] + u[zv.x + NN];
        const float s2 = u[zv.z] + u[zv.y + NN];
        const float s3 = u[zv.w] + u[zv.z + NN];

        float mloc = fmaxf(fmaxf(s0, s1), fmaxf(s2, s3));
#pragma unroll
        for (int off = 32; off > 0; off >>= 1) mloc = fmaxf(mloc, __shfl_xor(mloc, off));
        if (lane == 0) redm[w] = mloc;
        __syncthreads();                                   // B
        float M = redm[0];
#pragma unroll
        for (int i = 1; i < 8; ++i) M = fmaxf(M, redm[i]);

        const float e0 = __expf(s0 - M);
        const float e1 = __expf(s1 - M);
        const float e2 = __expf(s2 - M);
        const float e3 = __expf(s3 - M);
        float t = (e0 + e1) + (e2 + e3);
#pragma unroll
        for (int off = 32; off > 0; off >>= 1) t += __shfl_xor(t, off);
        if (lane == 0) redt[w] = t;
        __syncthreads();                                   // C
        float tot = redt[0];
#pragma unroll
        for (int i = 1; i < 8; ++i) tot += redt[i];
        const float inv = 1.f / tot;

        // scatter attn weights into wsf
        atomicAdd(&wsf[zv.x], e0);
        if (tid > 0) atomicAdd(&wsf[zp0 + NN], e0);
        atomicAdd(&wsf[zv.y], e1); atomicAdd(&wsf[zv.x + NN], e1);
        atomicAdd(&wsf[zv.z], e2); atomicAdd(&wsf[zv.y + NN], e2);
        atomicAdd(&wsf[zv.w], e3); atomicAdd(&wsf[zv.z + NN], e3);
        __syncthreads();                                   // D

        // thread (s, b16==b) captures its ws fragments (normalized, f32)
        if (b16 == b) {
#pragma unroll
            for (int i = 0; i < 16; ++i) {
                float4 v = ((const float4*)wsf)[s + 32 * i];
                wsr[i].x = v.x * inv; wsr[i].y = v.y * inv;
                wsr[i].z = v.z * inv; wsr[i].w = v.w * inv;
            }
        }
        __syncthreads();                                   // E (protect u/wsf)
    }

    // ---- land prefetched rows in LDS ----
#pragma unroll
    for (int k = 0; k < 8; ++k) rows[w][k * 64 + lane] = pf[k];
    __syncthreads();

    // ---- dot: acc[j] = sum_dg rows[j][dg] . ws[dg][b16] ----
    float acc[8];
#pragma unroll
    for (int j = 0; j < 8; ++j) acc[j] = 0.f;

#pragma unroll
    for (int it = 0; it < 16; ++it) {
        const int dg = s + 32 * it;
        const float4 wv = wsr[it];
#pragma unroll
        for (int j = 0; j < 8; ++j) {
            float4 rv = rows[j][dg];     // 16-lane broadcast read (bank-free)
            acc[j] += rv.x * wv.x + rv.y * wv.y + rv.z * wv.z + rv.w * wv.w;
        }
    }

    // reduce over s within wave (lanes b16, b16+16, +32, +48)
#pragma unroll
    for (int j = 0; j < 8; ++j) {
        float p = acc[j];
        p += __shfl_xor(p, 16);
        p += __shfl_xor(p, 32);
        acc[j] = p;
    }
    if (lane < 16) {
#pragma unroll
        for (int j = 0; j < 8; ++j) red[j][w][lane] = acc[j];
    }
    __syncthreads();

    if (tid < 64) {
        const int r = tid >> 4, bb = tid & 15;
        float A = 0.f, Fv = 0.f;
#pragma unroll
        for (int ww = 0; ww < 8; ++ww) {
            A  += red[2 * r + 0][ww][bb];
            Fv += red[2 * r + 1][ww][bb];
        }
        const float* __restrict__ Fl = (const float*)&rows[2 * r + 1][0];
        Fv += Fl[hdrsh[0][bb]] + Fl[hdrsh[1][bb]];
        const int n = 4 * g + r;
        out[(size_t)bb * NN + n]            = A + Fv;   // xi
        out[(size_t)(BB + bb) * NN + n]     = A;        // xi_A
        out[(size_t)(2 * BB + bb) * NN + n] = Fv;       // xi_F
    }
}

extern "C" void kernel_launch(void* const* d_in, const int* in_sizes, int n_in,
                              void* d_out, int out_size, void* d_ws, size_t ws_size,
                              hipStream_t stream) {
    const int*   z  = (const int*)d_in[0];
    const float* Fm = (const float*)d_in[1];
    const float* Vm = (const float*)d_in[2];
    const float* Wm = (const float*)d_in[3];
    float* out = (float*)d_out;

    ot_fused<<<256, 512, 0, stream>>>(z, Fm, Vm, Wm, out);
}

// Round 7
// 23.730 us; speedup vs baseline: 6.1788x; 6.1788x over previous
//
#include <hip/hip_runtime.h>

#define BB 16
#define HH 2048
#define NN 1024
#define DD 2048
#define DG4 (DD / 4)   // 512 float4-groups per row

// Workspace: int hdr[32] (d1[16], d2[16]); pad to 128 B; then
// wsB[DG4][BB] uint2 — 4 consecutive d packed as bf16x4 per batch (64 KB).

__device__ __forceinline__ unsigned short f2bf(float f) {
    unsigned u = __float_as_uint(f);
    u += 0x7fffu + ((u >> 16) & 1u);   // round-to-nearest-even
    return (unsigned short)(u >> 16);
}

// Kernel 1: 256 blocks x 512 threads.
//  - ALL blocks warm-read their 4 V/F rows (64 KB) -> pulls 16 MB into L3
//    concurrently with phase1 (kept live via empty asm).
//  - Blocks 0..15 run phase1 for batch b = blockIdx.x: scores -> softmax
//    (no max subtraction; |s| < 0.5) -> LDS scatter -> bf16 wsB + hdr.
__global__ __launch_bounds__(512) void ot_p1warm(const int* __restrict__ z,
                                                 const float* __restrict__ Fm,
                                                 const float* __restrict__ Vm,
                                                 const float* __restrict__ Wm,
                                                 int* __restrict__ hdr,
                                                 uint2* __restrict__ wsB) {
    __shared__ int   zsh[HH];
    __shared__ float u[DD];
    __shared__ float wsf[DD];
    __shared__ float redt[8];

    const int tid  = threadIdx.x;
    const int lane = tid & 63;
    const int w    = tid >> 6;
    const int g    = blockIdx.x;

    // ---- warm reads: V/F rows 4g..4g+3 (issued first, HBM latency hides) ----
    float4 pf[8];
    {
        const int r = w >> 1, m = w & 1;
        const float4* __restrict__ src =
            (const float4*)((m ? Fm : Vm) + (size_t)(4 * g + r) * DD);
#pragma unroll
        for (int k = 0; k < 8; ++k) pf[k] = src[k * 64 + lane];
    }

    if (g < BB) {
        const int b = g;
        // z tail -> d1,d2 (broadcast, no barrier needed)
        const int4 zt = ((const int4*)(z + (size_t)b * HH))[DG4 - 1];
        const int d1 = zt.w;          // z[H-1]     in [0, NN)
        const int d2 = zt.z + NN;     // z[H-2]+NN  in [NN, DD)

        // issue z row + both W rows
        const int4 zv = ((const int4*)(z + (size_t)b * HH))[tid];   // h = 4t..4t+3
        float4 wa = ((const float4*)(Wm + (size_t)d1 * DD))[tid];
        float4 wc = ((const float4*)(Wm + (size_t)d2 * DD))[tid];

        ((int4*)zsh)[tid] = zv;
        float4 uu;
        uu.x = wa.x + wc.x; uu.y = wa.y + wc.y;
        uu.z = wa.z + wc.z; uu.w = wa.w + wc.w;
        ((float4*)u)[tid] = uu;
        ((float4*)wsf)[tid] = make_float4(0.f, 0.f, 0.f, 0.f);
        __syncthreads();                                    // A

        const int zp0 = (tid > 0) ? zsh[4 * tid - 1] + NN : 0;
        const float s0 = u[zv.x] + ((tid > 0) ? u[zp0] : 0.f);
        const float s1 = u[zv.y] + u[zv.x + NN];
        const float s2 = u[zv.z] + u[zv.y + NN];
        const float s3 = u[zv.w] + u[zv.z + NN];

        // exp without max subtraction (|s| < 0.5): softmax-identical
        const float e0 = __expf(s0);
        const float e1 = __expf(s1);
        const float e2 = __expf(s2);
        const float e3 = __expf(s3);
        float t = (e0 + e1) + (e2 + e3);
#pragma unroll
        for (int off = 32; off > 0; off >>= 1) t += __shfl_xor(t, off);
        if (lane == 0) redt[w] = t;

        // scatter unnormalized weights
        atomicAdd(&wsf[zv.x], e0);
        if (tid > 0) atomicAdd(&wsf[zp0], e0);
        atomicAdd(&wsf[zv.y], e1); atomicAdd(&wsf[zv.x + NN], e1);
        atomicAdd(&wsf[zv.z], e2); atomicAdd(&wsf[zv.y + NN], e2);
        atomicAdd(&wsf[zv.w], e3); atomicAdd(&wsf[zv.z + NN], e3);
        __syncthreads();                                    // B

        float tot = redt[0];
#pragma unroll
        for (int i = 1; i < 8; ++i) tot += redt[i];
        const float inv = 1.f / tot;

        // pack bf16x4 per d-group, layout [dg][b]
        uint2 p;
        p.x = (unsigned)f2bf(wsf[4 * tid + 0] * inv)
            | ((unsigned)f2bf(wsf[4 * tid + 1] * inv) << 16);
        p.y = (unsigned)f2bf(wsf[4 * tid + 2] * inv)
            | ((unsigned)f2bf(wsf[4 * tid + 3] * inv) << 16);
        wsB[(size_t)tid * BB + b] = p;
        if (tid == 0) { hdr[b] = d1; hdr[BB + b] = d2; }
    }

    // keep warm loads alive (prevent DCE / load narrowing)
#pragma unroll
    for (int k = 0; k < 8; ++k)
        asm volatile("" :: "v"(pf[k].x), "v"(pf[k].y), "v"(pf[k].z), "v"(pf[k].w));
}

// Kernel 2 (unchanged from R5): block g computes rows n = 4g..4g+3 for all
// 16 batches. Thread (s = tid>>4 in 0..31, b = tid&15); ws packed in 32 VGPRs.
__global__ __launch_bounds__(512, 4) void ot_phase2(const float* __restrict__ V,
                                                    const float* __restrict__ F,
                                                    const int* __restrict__ hdr,
                                                    const uint2* __restrict__ wsB,
                                                    float* __restrict__ out) {
    const int tid  = threadIdx.x;
    const int lane = tid & 63;
    const int w    = tid >> 6;
    const int b    = lane & 15;
    const int s    = tid >> 4;            // 0..31
    const int g    = blockIdx.x;

    uint2 wsr[16];
#pragma unroll
    for (int i = 0; i < 16; ++i) wsr[i] = wsB[(size_t)(s + 32 * i) * BB + b];

    const float4* __restrict__ Vr0 = (const float4*)(V + (size_t)(4 * g + 0) * DD);
    const float4* __restrict__ Vr1 = (const float4*)(V + (size_t)(4 * g + 1) * DD);
    const float4* __restrict__ Vr2 = (const float4*)(V + (size_t)(4 * g + 2) * DD);
    const float4* __restrict__ Vr3 = (const float4*)(V + (size_t)(4 * g + 3) * DD);
    const float4* __restrict__ Fr0 = (const float4*)(F + (size_t)(4 * g + 0) * DD);
    const float4* __restrict__ Fr1 = (const float4*)(F + (size_t)(4 * g + 1) * DD);
    const float4* __restrict__ Fr2 = (const float4*)(F + (size_t)(4 * g + 2) * DD);
    const float4* __restrict__ Fr3 = (const float4*)(F + (size_t)(4 * g + 3) * DD);

    float acc[8];
#pragma unroll
    for (int j = 0; j < 8; ++j) acc[j] = 0.f;

#pragma unroll
    for (int it = 0; it < 16; ++it) {
        const int dg = s + 32 * it;
        const uint2 p = wsr[it];
        const float s0 = __uint_as_float(p.x << 16);
        const float s1 = __uint_as_float(p.x & 0xffff0000u);
        const float s2 = __uint_as_float(p.y << 16);
        const float s3 = __uint_as_float(p.y & 0xffff0000u);
        float4 v0 = Vr0[dg], v1 = Vr1[dg], v2 = Vr2[dg], v3 = Vr3[dg];
        float4 f0 = Fr0[dg], f1 = Fr1[dg], f2 = Fr2[dg], f3 = Fr3[dg];
        acc[0] += v0.x * s0 + v0.y * s1 + v0.z * s2 + v0.w * s3;
        acc[1] += f0.x * s0 + f0.y * s1 + f0.z * s2 + f0.w * s3;
        acc[2] += v1.x * s0 + v1.y * s1 + v1.z * s2 + v1.w * s3;
        acc[3] += f1.x * s0 + f1.y * s1 + f1.z * s2 + f1.w * s3;
        acc[4] += v2.x * s0 + v2.y * s1 + v2.z * s2 + v2.w * s3;
        acc[5] += f2.x * s0 + f2.y * s1 + f2.z * s2 + f2.w * s3;
        acc[6] += v3.x * s0 + v3.y * s1 + v3.z * s2 + v3.w * s3;
        acc[7] += f3.x * s0 + f3.y * s1 + f3.z * s2 + f3.w * s3;
    }

#pragma unroll
    for (int j = 0; j < 8; ++j) {
        float p = acc[j];
        p += __shfl_xor(p, 16);
        p += __shfl_xor(p, 32);
        acc[j] = p;
    }

    __shared__ float red[8][8][BB];
    if (lane < 16) {
#pragma unroll
        for (int j = 0; j < 8; ++j) red[j][w][b] = acc[j];
    }
    __syncthreads();

    if (tid < 64) {
        const int r = tid >> 4, bb = tid & 15;
        float A = 0.f, Fv = 0.f;
#pragma unroll
        for (int ww = 0; ww < 8; ++ww) {
            A  += red[2 * r + 0][ww][bb];
            Fv += red[2 * r + 1][ww][bb];
        }
        const int n = 4 * g + r;
        const float* __restrict__ Fr = F + (size_t)n * DD;
        Fv += Fr[hdr[bb]] + Fr[hdr[BB + bb]];
        out[(size_t)bb * NN + n]            = A + Fv;   // xi
        out[(size_t)(BB + bb) * NN + n]     = A;        // xi_A
        out[(size_t)(2 * BB + bb) * NN + n] = Fv;       // xi_F
    }
}

extern "C" void kernel_launch(void* const* d_in, const int* in_sizes, int n_in,
                              void* d_out, int out_size, void* d_ws, size_t ws_size,
                              hipStream_t stream) {
    const int*   z  = (const int*)d_in[0];
    const float* Fm = (const float*)d_in[1];
    const float* Vm = (const float*)d_in[2];
    const float* Wm = (const float*)d_in[3];
    float* out = (float*)d_out;

    int*   hdr = (int*)d_ws;
    uint2* wsB = (uint2*)((char*)d_ws + 128);

    ot_p1warm<<<256, 512, 0, stream>>>(z, Fm, Vm, Wm, hdr, wsB);
    ot_phase2<<<NN / 4, 512, 0, stream>>>(Vm, Fm, hdr, wsB, out);
}